// Round 1
// 1766.573 us; speedup vs baseline: 1.1790x; 1.1790x over previous
//
#include <hip/hip_runtime.h>
#include <math.h>

// BERTStudentPruner on MI355X — fp16x2 split-precision MFMA GEMMs, v2.
//
// v2 change: hoist ALL fp32->{hi,lo} fp16 splitting out of the GEMM main
// loops. X, W1, W2 are pre-split once into separate f16 hi/lo planes
// (memory-bound pass, ~140us); gemm1 writes H1 as two f16 planes. Both
// GEMMs then stage all four LDS tiles with global_load_lds width=16
// (zero staging VALU, zero ds_writes) — pure m97 pattern with 3x MFMA
// density. Numerics are bit-identical to v1 (same split ops, same MFMA
// order): absmax 0 preserved.
//
// Precision: a = a_hi + 2^-11 * a_lo, 3 MFMAs/tile (hi*hi; hi*lo+lo*hi),
// lo*lo dropped (~3e-8 abs).
//
// Extras: XOR k-chunk swizzle (linear LDS dest + inverse-swizzled global
// source; same XOR on ds_read) to cut read bank conflicts; XCD-bijective
// block remap so the 6 N-tiles of a row-block share one XCD's L2; rank
// kernel split 8-way per row. Falls back to the v1 pipeline if ws_size
// cannot hold the f16 planes (~810 MB).

typedef _Float16 f16;
typedef __attribute__((ext_vector_type(8))) _Float16 half8;
typedef __attribute__((ext_vector_type(4))) float f32x4;

#define BM 128
#define BN 128
#define BK 32
#define RS 40          // fallback-path LDS row stride (pad 32->40)
#define INV2048 (1.0f/2048.0f)

typedef __attribute__((address_space(3))) unsigned lds_u32;
typedef __attribute__((address_space(1))) const unsigned gbl_u32;
#define GLOAD16(g, l) __builtin_amdgcn_global_load_lds((gbl_u32*)(g), (lds_u32*)(l), 16, 0, 0)

union HU { unsigned short u; f16 f; };
static __device__ inline unsigned pack_hl(f16 h, f16 l) {
  HU a, b; a.f = h; b.f = l;
  return (unsigned)a.u | ((unsigned)b.u << 16);
}
static __device__ inline f16 u2h(unsigned short u) { HU c; c.u = u; return c.f; }

// Split 16 fp32 (in x[16]) into hi/lo half8 pairs (fallback path).
#define SPLIT16(x, h0, h1, l0, l1)                                   \
  {                                                                  \
    _Pragma("unroll")                                                \
    for (int e = 0; e < 8; ++e) {                                    \
      f16 ha = (f16)x[e];      float fa = (float)ha;                 \
      f16 hb = (f16)x[8 + e];  float fb = (float)hb;                 \
      h0[e] = ha; l0[e] = (f16)((x[e] - fa) * 2048.0f);              \
      h1[e] = hb; l1[e] = (f16)((x[8 + e] - fb) * 2048.0f);          \
    }                                                                \
  }

// ------------------------------------------------------------- presplit
// fp32 src[n] -> f16 hi[n], lo[n]. Vectorized, grid-stride.
__global__ __launch_bounds__(256) void presplit_kernel(
    const float* __restrict__ src, f16* __restrict__ hi,
    f16* __restrict__ lo, int n)
{
  int i = (blockIdx.x * 256 + threadIdx.x) * 8;
  const int stride = gridDim.x * 256 * 8;
  for (; i + 7 < n; i += stride) {
    float4 x0 = *(const float4*)(src + i);
    float4 x1 = *(const float4*)(src + i + 4);
    float xs[8] = {x0.x, x0.y, x0.z, x0.w, x1.x, x1.y, x1.z, x1.w};
    half8 h, l;
#pragma unroll
    for (int e = 0; e < 8; ++e) {
      f16 hv = (f16)xs[e];
      h[e] = hv;
      l[e] = (f16)((xs[e] - (float)hv) * 2048.0f);
    }
    *(half8*)(hi + i) = h;
    *(half8*)(lo + i) = l;
  }
}

// -------------------------------------------------- split-plane GEMM
// A planes [M,K] f16 hi/lo, B planes [N,K] f16 hi/lo.
// FUSE=0: out = relu(A@B^T + bias) split to Oh/Ol planes  (gemm1)
// FUSE=1: ylogit += relu(A@B^T + bias) @ w3 (atomicAdd)   (gemm2)
template<int FUSE>
__global__ __launch_bounds__(256, 2) void gemm_split_kernel(
    const f16* __restrict__ Ahg, const f16* __restrict__ Alg,
    const f16* __restrict__ Bhg, const f16* __restrict__ Blg,
    const float* __restrict__ bias, const float* __restrict__ w3,
    f16* __restrict__ Oh, f16* __restrict__ Ol,
    float* __restrict__ ylogit, int M, int N, int K)
{
  __shared__ f16 L[4 * BM * BK];   // planes Ah,Al,Bh,Bl — 8 KB each, linear

  // XCD-bijective remap (gridDim.x % 8 == 0): consecutive n on one XCD,
  // so the 6 N-tiles sharing an A row-panel hit the same L2.
  const int nwg = gridDim.x;
  const int cpx = nwg >> 3;
  const int n = ((int)blockIdx.x & 7) * cpx + ((int)blockIdx.x >> 3);
  const int nbn = N / BN;
  const int bn = (n % nbn) * BN;
  const int bm = (n / nbn) * BM;

  const int t = threadIdx.x;
  const int lane = t & 63;
  const int wv = t >> 6;
  const int wm = (wv >> 1) * 64;
  const int wn = (wv & 1) * 64;
  const int i16 = lane & 15;
  const int quad = lane >> 4;
  const int swq = quad ^ (i16 & 3);   // XOR-swizzled k-chunk for frag reads

  // Staging: wave wv stages plane wv. 512 16B-chunks/plane = 8 issues x 64
  // lanes. LDS dest is LINEAR in lane order (global_load_lds requirement);
  // the swizzle is applied on the SOURCE index: LDS[row][c] = G[row][c^(row&3)].
  const int srow = lane >> 2;               // row within issue's 16-row group
  const int sch = (lane & 3) ^ (srow & 3);  // inverse-swizzled source chunk
  const f16* sp;
  if (wv == 0)      sp = Ahg + (size_t)bm * K;
  else if (wv == 1) sp = Alg + (size_t)bm * K;
  else if (wv == 2) sp = Bhg + (size_t)bn * K;
  else              sp = Blg + (size_t)bn * K;
  const f16* sbase = sp + (size_t)srow * K + sch * 8;
  char* lwb = (char*)L + wv * 8192;

  const f16* LAh = L;
  const f16* LAl = L + BM * BK;
  const f16* LBh = L + 2 * BM * BK;
  const f16* LBl = L + 3 * BM * BK;

  f32x4 acc1[4][4] = {};
  f32x4 acc2[4][4] = {};

  for (int k0 = 0; k0 < K; k0 += BK) {
    __syncthreads();                        // LDS consumed by prev iter
#pragma unroll
    for (int j = 0; j < 8; ++j)
      GLOAD16(sbase + (size_t)j * 16 * K + k0, lwb + j * 1024);
    __syncthreads();                        // drains vmcnt (compiler-emitted)

    half8 fah[4], fal[4], fbh[4], fbl[4];
#pragma unroll
    for (int i = 0; i < 4; ++i) {
      const int ao = (wm + i * 16 + i16) * BK + swq * 8;
      const int bo = (wn + i * 16 + i16) * BK + swq * 8;
      fah[i] = *(const half8*)&LAh[ao];
      fal[i] = *(const half8*)&LAl[ao];
      fbh[i] = *(const half8*)&LBh[bo];
      fbl[i] = *(const half8*)&LBl[bo];
    }
#pragma unroll
    for (int im = 0; im < 4; ++im)
#pragma unroll
      for (int in = 0; in < 4; ++in) {
        acc1[im][in] = __builtin_amdgcn_mfma_f32_16x16x32_f16(
            fah[im], fbh[in], acc1[im][in], 0, 0, 0);
        acc2[im][in] = __builtin_amdgcn_mfma_f32_16x16x32_f16(
            fah[im], fbl[in], acc2[im][in], 0, 0, 0);
        acc2[im][in] = __builtin_amdgcn_mfma_f32_16x16x32_f16(
            fal[im], fbh[in], acc2[im][in], 0, 0, 0);
      }
  }

  if (FUSE == 0) {
    // relu(acc + bias), split to planes.
#pragma unroll
    for (int in = 0; in < 4; ++in) {
      const int col = bn + wn + in * 16 + i16;
      const float bv = bias[col];
#pragma unroll
      for (int im = 0; im < 4; ++im)
#pragma unroll
        for (int reg = 0; reg < 4; ++reg) {
          const int row = bm + wm + im * 16 + quad * 4 + reg;
          float v = acc1[im][in][reg] + acc2[im][in][reg] * INV2048 + bv;
          v = v > 0.f ? v : 0.f;
          f16 hv = (f16)v;
          Oh[(size_t)row * N + col] = hv;
          Ol[(size_t)row * N + col] = (f16)((v - (float)hv) * 2048.0f);
        }
    }
  } else {
    // relu(acc + bias) dot w3 over this tile's cols -> atomicAdd.
    float psum[4][4];
#pragma unroll
    for (int im = 0; im < 4; ++im)
#pragma unroll
      for (int reg = 0; reg < 4; ++reg) psum[im][reg] = 0.f;

#pragma unroll
    for (int in = 0; in < 4; ++in) {
      const int col = bn + wn + in * 16 + i16;
      const float bv = bias[col];
      const float wv3 = w3[col];
#pragma unroll
      for (int im = 0; im < 4; ++im)
#pragma unroll
        for (int reg = 0; reg < 4; ++reg) {
          float v = acc1[im][in][reg] + acc2[im][in][reg] * INV2048 + bv;
          v = v > 0.f ? v : 0.f;
          psum[im][reg] = fmaf(v, wv3, psum[im][reg]);
        }
    }
#pragma unroll
    for (int off = 1; off < 16; off <<= 1)
#pragma unroll
      for (int im = 0; im < 4; ++im)
#pragma unroll
        for (int reg = 0; reg < 4; ++reg)
          psum[im][reg] += __shfl_xor(psum[im][reg], off, 64);

    if (i16 == 0) {
#pragma unroll
      for (int im = 0; im < 4; ++im)
#pragma unroll
        for (int reg = 0; reg < 4; ++reg)
          atomicAdd(&ylogit[bm + wm + im * 16 + quad * 4 + reg], psum[im][reg]);
    }
  }
}

// ---------------------------------------------------------------- GEMM 1 (fallback)
__global__ __launch_bounds__(256, 2) void gemm1_fb_kernel(
    const float* __restrict__ A, const float* __restrict__ B,
    const float* __restrict__ bias, unsigned* __restrict__ H1,
    int M, int N, int K)
{
  __shared__ f16 Ah[BM * RS], Al[BM * RS], Bh[BN * RS], Bl[BN * RS];

  const int bn = blockIdx.x * BN;
  const int bm = blockIdx.y * BM;
  const int t = threadIdx.x;
  const int r = t >> 1;
  const int h = t & 1;

  const int lane = t & 63;
  const int wv = t >> 6;
  const int wm = (wv >> 1) * 64;
  const int wn = (wv & 1) * 64;
  const int i16 = lane & 15;
  const int quad = lane >> 4;

  f32x4 acc1[4][4] = {};
  f32x4 acc2[4][4] = {};

  const float* Ag = A + (size_t)(bm + r) * K + h * 16;
  const float* Bg = B + (size_t)(bn + r) * K + h * 16;

  for (int k0 = 0; k0 < K; k0 += BK) {
    float xa[16], xb[16];
    *(float4*)&xa[0]  = *(const float4*)(Ag + k0);
    *(float4*)&xa[4]  = *(const float4*)(Ag + k0 + 4);
    *(float4*)&xa[8]  = *(const float4*)(Ag + k0 + 8);
    *(float4*)&xa[12] = *(const float4*)(Ag + k0 + 12);
    *(float4*)&xb[0]  = *(const float4*)(Bg + k0);
    *(float4*)&xb[4]  = *(const float4*)(Bg + k0 + 4);
    *(float4*)&xb[8]  = *(const float4*)(Bg + k0 + 8);
    *(float4*)&xb[12] = *(const float4*)(Bg + k0 + 12);

    half8 ah0, ah1, al0, al1, bh0, bh1, bl0, bl1;
    SPLIT16(xa, ah0, ah1, al0, al1);
    SPLIT16(xb, bh0, bh1, bl0, bl1);

    __syncthreads();
    const int so = r * RS + h * 16;
    *(half8*)&Ah[so] = ah0; *(half8*)&Ah[so + 8] = ah1;
    *(half8*)&Al[so] = al0; *(half8*)&Al[so + 8] = al1;
    *(half8*)&Bh[so] = bh0; *(half8*)&Bh[so + 8] = bh1;
    *(half8*)&Bl[so] = bl0; *(half8*)&Bl[so + 8] = bl1;
    __syncthreads();

    half8 fah[4], fal[4], fbh[4], fbl[4];
#pragma unroll
    for (int i = 0; i < 4; ++i) {
      const int ao = (wm + i * 16 + i16) * RS + quad * 8;
      const int bo = (wn + i * 16 + i16) * RS + quad * 8;
      fah[i] = *(const half8*)&Ah[ao];
      fal[i] = *(const half8*)&Al[ao];
      fbh[i] = *(const half8*)&Bh[bo];
      fbl[i] = *(const half8*)&Bl[bo];
    }
#pragma unroll
    for (int im = 0; im < 4; ++im)
#pragma unroll
      for (int in = 0; in < 4; ++in) {
        acc1[im][in] = __builtin_amdgcn_mfma_f32_16x16x32_f16(
            fah[im], fbh[in], acc1[im][in], 0, 0, 0);
        acc2[im][in] = __builtin_amdgcn_mfma_f32_16x16x32_f16(
            fah[im], fbl[in], acc2[im][in], 0, 0, 0);
        acc2[im][in] = __builtin_amdgcn_mfma_f32_16x16x32_f16(
            fal[im], fbh[in], acc2[im][in], 0, 0, 0);
      }
  }

#pragma unroll
  for (int in = 0; in < 4; ++in) {
    const int col = bn + wn + in * 16 + i16;
    const float bv = bias[col];
#pragma unroll
    for (int im = 0; im < 4; ++im) {
#pragma unroll
      for (int reg = 0; reg < 4; ++reg) {
        const int row = bm + wm + im * 16 + quad * 4 + reg;
        float v = acc1[im][in][reg] + acc2[im][in][reg] * INV2048 + bv;
        v = v > 0.f ? v : 0.f;
        f16 hv = (f16)v;
        f16 lv = (f16)((v - (float)hv) * 2048.0f);
        H1[(size_t)row * N + col] = pack_hl(hv, lv);
      }
    }
  }
}

// ---------------------------------------------------------------- GEMM 2 (fallback)
__global__ __launch_bounds__(256, 2) void gemm2_fb_kernel(
    const unsigned* __restrict__ A, const float* __restrict__ B,
    const float* __restrict__ bias, const float* __restrict__ w3,
    float* __restrict__ ylogit, int M, int N, int K)
{
  __shared__ f16 Ah[BM * RS], Al[BM * RS], Bh[BN * RS], Bl[BN * RS];

  const int bn = blockIdx.x * BN;
  const int bm = blockIdx.y * BM;
  const int t = threadIdx.x;
  const int r = t >> 1;
  const int h = t & 1;

  const int lane = t & 63;
  const int wv = t >> 6;
  const int wm = (wv >> 1) * 64;
  const int wn = (wv & 1) * 64;
  const int i16 = lane & 15;
  const int quad = lane >> 4;

  f32x4 acc1[4][4] = {};
  f32x4 acc2[4][4] = {};

  const unsigned* Ag = A + (size_t)(bm + r) * K + h * 16;
  const float* Bg = B + (size_t)(bn + r) * K + h * 16;

  for (int k0 = 0; k0 < K; k0 += BK) {
    unsigned ua[16];
    float xb[16];
    *(uint4*)&ua[0]  = *(const uint4*)(Ag + k0);
    *(uint4*)&ua[4]  = *(const uint4*)(Ag + k0 + 4);
    *(uint4*)&ua[8]  = *(const uint4*)(Ag + k0 + 8);
    *(uint4*)&ua[12] = *(const uint4*)(Ag + k0 + 12);
    *(float4*)&xb[0]  = *(const float4*)(Bg + k0);
    *(float4*)&xb[4]  = *(const float4*)(Bg + k0 + 4);
    *(float4*)&xb[8]  = *(const float4*)(Bg + k0 + 8);
    *(float4*)&xb[12] = *(const float4*)(Bg + k0 + 12);

    half8 ah0, ah1, al0, al1, bh0, bh1, bl0, bl1;
#pragma unroll
    for (int e = 0; e < 8; ++e) {
      ah0[e] = u2h((unsigned short)(ua[e] & 0xffffu));
      al0[e] = u2h((unsigned short)(ua[e] >> 16));
      ah1[e] = u2h((unsigned short)(ua[8 + e] & 0xffffu));
      al1[e] = u2h((unsigned short)(ua[8 + e] >> 16));
    }
    SPLIT16(xb, bh0, bh1, bl0, bl1);

    __syncthreads();
    const int so = r * RS + h * 16;
    *(half8*)&Ah[so] = ah0; *(half8*)&Ah[so + 8] = ah1;
    *(half8*)&Al[so] = al0; *(half8*)&Al[so + 8] = al1;
    *(half8*)&Bh[so] = bh0; *(half8*)&Bh[so + 8] = bh1;
    *(half8*)&Bl[so] = bl0; *(half8*)&Bl[so + 8] = bl1;
    __syncthreads();

    half8 fah[4], fal[4], fbh[4], fbl[4];
#pragma unroll
    for (int i = 0; i < 4; ++i) {
      const int ao = (wm + i * 16 + i16) * RS + quad * 8;
      const int bo = (wn + i * 16 + i16) * RS + quad * 8;
      fah[i] = *(const half8*)&Ah[ao];
      fal[i] = *(const half8*)&Al[ao];
      fbh[i] = *(const half8*)&Bh[bo];
      fbl[i] = *(const half8*)&Bl[bo];
    }
#pragma unroll
    for (int im = 0; im < 4; ++im)
#pragma unroll
      for (int in = 0; in < 4; ++in) {
        acc1[im][in] = __builtin_amdgcn_mfma_f32_16x16x32_f16(
            fah[im], fbh[in], acc1[im][in], 0, 0, 0);
        acc2[im][in] = __builtin_amdgcn_mfma_f32_16x16x32_f16(
            fah[im], fbl[in], acc2[im][in], 0, 0, 0);
        acc2[im][in] = __builtin_amdgcn_mfma_f32_16x16x32_f16(
            fal[im], fbh[in], acc2[im][in], 0, 0, 0);
      }
  }

  float psum[4][4];
#pragma unroll
  for (int im = 0; im < 4; ++im)
#pragma unroll
    for (int reg = 0; reg < 4; ++reg) psum[im][reg] = 0.f;

#pragma unroll
  for (int in = 0; in < 4; ++in) {
    const int col = bn + wn + in * 16 + i16;
    const float bv = bias[col];
    const float wv3 = w3[col];
#pragma unroll
    for (int im = 0; im < 4; ++im)
#pragma unroll
      for (int reg = 0; reg < 4; ++reg) {
        float v = acc1[im][in][reg] + acc2[im][in][reg] * INV2048 + bv;
        v = v > 0.f ? v : 0.f;
        psum[im][reg] = fmaf(v, wv3, psum[im][reg]);
      }
  }
#pragma unroll
  for (int off = 1; off < 16; off <<= 1)
#pragma unroll
    for (int im = 0; im < 4; ++im)
#pragma unroll
      for (int reg = 0; reg < 4; ++reg)
        psum[im][reg] += __shfl_xor(psum[im][reg], off, 64);

  if (i16 == 0) {
#pragma unroll
    for (int im = 0; im < 4; ++im)
#pragma unroll
      for (int reg = 0; reg < 4; ++reg)
        atomicAdd(&ylogit[bm + wm + im * 16 + quad * 4 + reg], psum[im][reg]);
  }
}

// ---------------------------------------------------------------- sigmoid
__global__ void sigmoid_kernel(const float* __restrict__ logit,
                               const float* __restrict__ b3,
                               float* __restrict__ ysoft, int n)
{
  int i = blockIdx.x * blockDim.x + threadIdx.x;
  if (i < n) {
    float x = logit[i] + b3[0];
    ysoft[i] = 1.f / (1.f + expf(-x));
  }
}

// ------------------------------------------------------------------ rank
// 8 blocks per row: block (b, part) computes out[part*256 .. part*256+255].
__global__ __launch_bounds__(256) void rank_kernel(
    const float* __restrict__ ysoft, float* __restrict__ yhard,
    const int* __restrict__ kptr, int S)
{
  __shared__ float row[2048];
  const int b = blockIdx.x;
  const int part = blockIdx.y;
  const float* y = ysoft + (size_t)b * S;
  float* out = yhard + (size_t)b * S;
  const int kk = *kptr;

  for (int i = threadIdx.x; i < S; i += 256) row[i] = y[i];
  __syncthreads();

  const int j = part * 256 + threadIdx.x;
  if (j >= S) return;
  if (j == 0) { out[0] = 1.0f; return; }
  const float v = row[j];
  int cnt = 1;  // token 0 always strictly smaller
  for (int i = 1; i < S; ++i) {
    float u = row[i];
    if (u < v || (u == v && i < j)) ++cnt;
  }
  out[j] = (cnt < kk) ? 1.0f : 0.0f;
}

// ------------------------------------------------------------------ launch
extern "C" void kernel_launch(void* const* d_in, const int* in_sizes, int n_in,
                              void* d_out, int out_size, void* d_ws, size_t ws_size,
                              hipStream_t stream)
{
  const float* X  = (const float*)d_in[0];
  const float* W1 = (const float*)d_in[1];
  const float* b1 = (const float*)d_in[2];
  const float* W2 = (const float*)d_in[3];
  const float* b2 = (const float*)d_in[4];
  const float* W3 = (const float*)d_in[5];
  const float* b3 = (const float*)d_in[6];
  const int*  kpt = (const int*)d_in[7];

  const int D = 768;
  const int M = in_sizes[0] / D;   // 131072
  const int S = 2048;
  const int Bb = M / S;            // 64

  float* ylogit = (float*)d_out;           // first M floats (scratch)
  float* yhard  = (float*)d_out;
  float* ysoft  = ((float*)d_out) + M;

  const size_t nX = (size_t)M * D;
  const size_t nW = (size_t)D * D;
  const size_t needA = (4 * nX + 4 * nW) * sizeof(f16);  // ~810 MB

  dim3 blk(256);

  if (ws_size >= needA) {
    f16* Xh  = (f16*)d_ws;
    f16* Xl  = Xh + nX;
    f16* W1h = Xl + nX;
    f16* W1l = W1h + nW;
    f16* W2h = W1l + nW;
    f16* W2l = W2h + nW;
    f16* H1h = W2l + nW;
    f16* H1l = H1h + nX;

    presplit_kernel<<<dim3(2048), blk, 0, stream>>>(X, Xh, Xl, (int)nX);
    presplit_kernel<<<dim3(288), blk, 0, stream>>>(W1, W1h, W1l, (int)nW);
    presplit_kernel<<<dim3(288), blk, 0, stream>>>(W2, W2h, W2l, (int)nW);
    hipMemsetAsync(ylogit, 0, (size_t)M * sizeof(float), stream);

    dim3 g((D / BN) * (M / BM));  // 6144, 1-D (decoded + XCD-remapped in-kernel)
    gemm_split_kernel<0><<<g, blk, 0, stream>>>(
        Xh, Xl, W1h, W1l, b1, nullptr, H1h, H1l, nullptr, M, D, D);
    gemm_split_kernel<1><<<g, blk, 0, stream>>>(
        H1h, H1l, W2h, W2l, b2, W3, nullptr, nullptr, ylogit, M, D, D);
  } else {
    // Fallback: v1 pipeline (packed {hi,lo} H1 in ws, in-kernel split).
    unsigned* H1 = (unsigned*)d_ws;
    hipMemsetAsync(ylogit, 0, (size_t)M * sizeof(float), stream);
    dim3 g(D / BN, M / BM);
    gemm1_fb_kernel<<<g, blk, 0, stream>>>(X, W1, b1, H1, M, D, D);
    gemm2_fb_kernel<<<g, blk, 0, stream>>>(H1, W2, b2, W3, ylogit, M, D, D);
  }

  sigmoid_kernel<<<dim3((M + 255) / 256), blk, 0, stream>>>(ylogit, b3, ysoft, M);
  rank_kernel<<<dim3(Bb, 8), blk, 0, stream>>>(ysoft, yhard, kpt, S);
}

// Round 2
// 1733.876 us; speedup vs baseline: 1.2012x; 1.0189x over previous
//
#include <hip/hip_runtime.h>
#include <math.h>

// BERTStudentPruner on MI355X — fp16x2 split-precision MFMA GEMMs, v3.
//
// v3 changes (both GEMMs, bit-identical numerics to v2):
//  1. Double-buffered LDS (2x32KB) with STAGE(t+1) issued BEFORE the MFMA
//     cluster of tile t; single __syncthreads() per K-step supplies the
//     vmcnt(0)+lgkmcnt(0) drain AFTER compute — staging latency hides
//     under the 48-MFMA cluster instead of being serially exposed
//     (T3-minimum 2-phase recipe; v2 drained BEFORE compute).
//  2. Corrected LDS XOR swizzle: chunk ^= (row>>1)&3 (was row&3).
//     slot8 = (row&1)*4 + chunk is now bijective over 8 consecutive rows
//     -> 2 lanes/bank-slot (free) instead of 4-way.
//
// Precision: a = a_hi + 2^-11 * a_lo, 3 MFMAs/tile (hi*hi; hi*lo+lo*hi),
// lo*lo dropped (~3e-8 abs). X, W1, W2 pre-split once into f16 hi/lo
// planes; gemm1 writes H1 as two planes; zero conversion VALU in-loop.

typedef _Float16 f16;
typedef __attribute__((ext_vector_type(8))) _Float16 half8;
typedef __attribute__((ext_vector_type(4))) float f32x4;

#define BM 128
#define BN 128
#define BK 32
#define RS 40          // fallback-path LDS row stride (pad 32->40)
#define INV2048 (1.0f/2048.0f)
#define PLANE (BM * BK)          // 4096 f16 = 8192 B per plane
#define BUFH  (4 * PLANE)        // 4 planes per buffer (f16 elems)

typedef __attribute__((address_space(3))) unsigned lds_u32;
typedef __attribute__((address_space(1))) const unsigned gbl_u32;
#define GLOAD16(g, l) __builtin_amdgcn_global_load_lds((gbl_u32*)(g), (lds_u32*)(l), 16, 0, 0)

union HU { unsigned short u; f16 f; };
static __device__ inline unsigned pack_hl(f16 h, f16 l) {
  HU a, b; a.f = h; b.f = l;
  return (unsigned)a.u | ((unsigned)b.u << 16);
}
static __device__ inline f16 u2h(unsigned short u) { HU c; c.u = u; return c.f; }

// Split 16 fp32 (in x[16]) into hi/lo half8 pairs (fallback path).
#define SPLIT16(x, h0, h1, l0, l1)                                   \
  {                                                                  \
    _Pragma("unroll")                                                \
    for (int e = 0; e < 8; ++e) {                                    \
      f16 ha = (f16)x[e];      float fa = (float)ha;                 \
      f16 hb = (f16)x[8 + e];  float fb = (float)hb;                 \
      h0[e] = ha; l0[e] = (f16)((x[e] - fa) * 2048.0f);              \
      h1[e] = hb; l1[e] = (f16)((x[8 + e] - fb) * 2048.0f);          \
    }                                                                \
  }

// ------------------------------------------------------------- presplit
__global__ __launch_bounds__(256) void presplit_kernel(
    const float* __restrict__ src, f16* __restrict__ hi,
    f16* __restrict__ lo, int n)
{
  int i = (blockIdx.x * 256 + threadIdx.x) * 8;
  const int stride = gridDim.x * 256 * 8;
  for (; i + 7 < n; i += stride) {
    float4 x0 = *(const float4*)(src + i);
    float4 x1 = *(const float4*)(src + i + 4);
    float xs[8] = {x0.x, x0.y, x0.z, x0.w, x1.x, x1.y, x1.z, x1.w};
    half8 h, l;
#pragma unroll
    for (int e = 0; e < 8; ++e) {
      f16 hv = (f16)xs[e];
      h[e] = hv;
      l[e] = (f16)((xs[e] - (float)hv) * 2048.0f);
    }
    *(half8*)(hi + i) = h;
    *(half8*)(lo + i) = l;
  }
}

// -------------------------------------------------- split-plane GEMM
// A planes [M,K] f16 hi/lo, B planes [N,K] f16 hi/lo.
// FUSE=0: out = relu(A@B^T + bias) split to Oh/Ol planes  (gemm1)
// FUSE=1: ylogit += relu(A@B^T + bias) @ w3 (atomicAdd)   (gemm2)
template<int FUSE>
__global__ __launch_bounds__(256, 2) void gemm_split_kernel(
    const f16* __restrict__ Ahg, const f16* __restrict__ Alg,
    const f16* __restrict__ Bhg, const f16* __restrict__ Blg,
    const float* __restrict__ bias, const float* __restrict__ w3,
    f16* __restrict__ Oh, f16* __restrict__ Ol,
    float* __restrict__ ylogit, int M, int N, int K)
{
  // Double-buffered: 2 x {Ah,Al,Bh,Bl} planes, linear layout, 64 KB.
  __shared__ f16 L[2 * BUFH];

  // XCD-bijective remap (gridDim.x % 8 == 0): consecutive n on one XCD,
  // so the 6 N-tiles sharing an A row-panel hit the same L2.
  const int nwg = gridDim.x;
  const int cpx = nwg >> 3;
  const int n = ((int)blockIdx.x & 7) * cpx + ((int)blockIdx.x >> 3);
  const int nbn = N / BN;
  const int bn = (n % nbn) * BN;
  const int bm = (n / nbn) * BM;

  const int t = threadIdx.x;
  const int lane = t & 63;
  const int wv = t >> 6;
  const int wm = (wv >> 1) * 64;
  const int wn = (wv & 1) * 64;
  const int i16 = lane & 15;
  const int quad = lane >> 4;
  // Read-side XOR swizzle: global k-chunk `quad` of row r lives in LDS
  // slot quad ^ ((r>>1)&3). Row base (wm/wn + i*16) is 0 mod 16, so only
  // i16 contributes: slot8 = (i16&1)*4 + swq is bijective over i16=0..7
  // -> 2-way bank aliasing (free).
  const int swq = quad ^ ((i16 >> 1) & 3);

  // Staging: wave wv stages plane wv. LDS dest is LINEAR in lane order
  // (global_load_lds requirement); the swizzle is applied on the SOURCE
  // chunk index with the same involution.
  const int srow = lane >> 2;                      // row in 16-row group
  const int sch = (lane & 3) ^ ((srow >> 1) & 3);  // inverse-swizzled chunk
  const f16* sp;
  if (wv == 0)      sp = Ahg + (size_t)bm * K;
  else if (wv == 1) sp = Alg + (size_t)bm * K;
  else if (wv == 2) sp = Bhg + (size_t)bn * K;
  else              sp = Blg + (size_t)bn * K;
  const f16* sbase = sp + (size_t)srow * K + sch * 8;

  f32x4 acc1[4][4] = {};
  f32x4 acc2[4][4] = {};

  // Prologue: stage K-tile 0 into buffer 0.
#pragma unroll
  for (int j = 0; j < 8; ++j)
    GLOAD16(sbase + (size_t)j * 16 * K, (char*)L + wv * 8192 + j * 1024);
  __syncthreads();

  int cur = 0;
  for (int k0 = 0; k0 < K; k0 += BK) {
    const f16* Lb  = L + cur * BUFH;
    const f16* LAh = Lb;
    const f16* LAl = Lb + PLANE;
    const f16* LBh = Lb + 2 * PLANE;
    const f16* LBl = Lb + 3 * PLANE;

    // Issue fragment ds_reads for the CURRENT tile first...
    half8 fah[4], fal[4], fbh[4], fbl[4];
#pragma unroll
    for (int i = 0; i < 4; ++i) {
      const int ao = (wm + i * 16 + i16) * BK + swq * 8;
      const int bo = (wn + i * 16 + i16) * BK + swq * 8;
      fah[i] = *(const half8*)&LAh[ao];
      fal[i] = *(const half8*)&LAl[ao];
      fbh[i] = *(const half8*)&LBh[bo];
      fbl[i] = *(const half8*)&LBl[bo];
    }

    // ...then issue the NEXT tile's staging loads (they fly during MFMA;
    // the only vmcnt(0) drain is at the end-of-iteration barrier).
    if (k0 + BK < K) {
      char* lwb = (char*)L + (cur ^ 1) * (BUFH * 2) + wv * 8192;
#pragma unroll
      for (int j = 0; j < 8; ++j)
        GLOAD16(sbase + (size_t)j * 16 * K + (k0 + BK), lwb + j * 1024);
    }
    __builtin_amdgcn_sched_barrier(0);  // keep issues above the MFMA cluster

#pragma unroll
    for (int im = 0; im < 4; ++im)
#pragma unroll
      for (int in = 0; in < 4; ++in) {
        acc1[im][in] = __builtin_amdgcn_mfma_f32_16x16x32_f16(
            fah[im], fbh[in], acc1[im][in], 0, 0, 0);
        acc2[im][in] = __builtin_amdgcn_mfma_f32_16x16x32_f16(
            fah[im], fbl[in], acc2[im][in], 0, 0, 0);
        acc2[im][in] = __builtin_amdgcn_mfma_f32_16x16x32_f16(
            fal[im], fbh[in], acc2[im][in], 0, 0, 0);
      }

    __syncthreads();   // drains vmcnt(0)+lgkmcnt(0) AFTER the MFMA cluster
    cur ^= 1;
  }

  if (FUSE == 0) {
    // relu(acc + bias), split to planes.
#pragma unroll
    for (int in = 0; in < 4; ++in) {
      const int col = bn + wn + in * 16 + i16;
      const float bv = bias[col];
#pragma unroll
      for (int im = 0; im < 4; ++im)
#pragma unroll
        for (int reg = 0; reg < 4; ++reg) {
          const int row = bm + wm + im * 16 + quad * 4 + reg;
          float v = acc1[im][in][reg] + acc2[im][in][reg] * INV2048 + bv;
          v = v > 0.f ? v : 0.f;
          f16 hv = (f16)v;
          Oh[(size_t)row * N + col] = hv;
          Ol[(size_t)row * N + col] = (f16)((v - (float)hv) * 2048.0f);
        }
    }
  } else {
    // relu(acc + bias) dot w3 over this tile's cols -> atomicAdd.
    float psum[4][4];
#pragma unroll
    for (int im = 0; im < 4; ++im)
#pragma unroll
      for (int reg = 0; reg < 4; ++reg) psum[im][reg] = 0.f;

#pragma unroll
    for (int in = 0; in < 4; ++in) {
      const int col = bn + wn + in * 16 + i16;
      const float bv = bias[col];
      const float wv3 = w3[col];
#pragma unroll
      for (int im = 0; im < 4; ++im)
#pragma unroll
        for (int reg = 0; reg < 4; ++reg) {
          float v = acc1[im][in][reg] + acc2[im][in][reg] * INV2048 + bv;
          v = v > 0.f ? v : 0.f;
          psum[im][reg] = fmaf(v, wv3, psum[im][reg]);
        }
    }
#pragma unroll
    for (int off = 1; off < 16; off <<= 1)
#pragma unroll
      for (int im = 0; im < 4; ++im)
#pragma unroll
        for (int reg = 0; reg < 4; ++reg)
          psum[im][reg] += __shfl_xor(psum[im][reg], off, 64);

    if (i16 == 0) {
#pragma unroll
      for (int im = 0; im < 4; ++im)
#pragma unroll
        for (int reg = 0; reg < 4; ++reg)
          atomicAdd(&ylogit[bm + wm + im * 16 + quad * 4 + reg], psum[im][reg]);
    }
  }
}

// ---------------------------------------------------------------- GEMM 1 (fallback)
__global__ __launch_bounds__(256, 2) void gemm1_fb_kernel(
    const float* __restrict__ A, const float* __restrict__ B,
    const float* __restrict__ bias, unsigned* __restrict__ H1,
    int M, int N, int K)
{
  __shared__ f16 Ah[BM * RS], Al[BM * RS], Bh[BN * RS], Bl[BN * RS];

  const int bn = blockIdx.x * BN;
  const int bm = blockIdx.y * BM;
  const int t = threadIdx.x;
  const int r = t >> 1;
  const int h = t & 1;

  const int lane = t & 63;
  const int wv = t >> 6;
  const int wm = (wv >> 1) * 64;
  const int wn = (wv & 1) * 64;
  const int i16 = lane & 15;
  const int quad = lane >> 4;

  f32x4 acc1[4][4] = {};
  f32x4 acc2[4][4] = {};

  const float* Ag = A + (size_t)(bm + r) * K + h * 16;
  const float* Bg = B + (size_t)(bn + r) * K + h * 16;

  for (int k0 = 0; k0 < K; k0 += BK) {
    float xa[16], xb[16];
    *(float4*)&xa[0]  = *(const float4*)(Ag + k0);
    *(float4*)&xa[4]  = *(const float4*)(Ag + k0 + 4);
    *(float4*)&xa[8]  = *(const float4*)(Ag + k0 + 8);
    *(float4*)&xa[12] = *(const float4*)(Ag + k0 + 12);
    *(float4*)&xb[0]  = *(const float4*)(Bg + k0);
    *(float4*)&xb[4]  = *(const float4*)(Bg + k0 + 4);
    *(float4*)&xb[8]  = *(const float4*)(Bg + k0 + 8);
    *(float4*)&xb[12] = *(const float4*)(Bg + k0 + 12);

    half8 ah0, ah1, al0, al1, bh0, bh1, bl0, bl1;
    SPLIT16(xa, ah0, ah1, al0, al1);
    SPLIT16(xb, bh0, bh1, bl0, bl1);

    __syncthreads();
    const int so = r * RS + h * 16;
    *(half8*)&Ah[so] = ah0; *(half8*)&Ah[so + 8] = ah1;
    *(half8*)&Al[so] = al0; *(half8*)&Al[so + 8] = al1;
    *(half8*)&Bh[so] = bh0; *(half8*)&Bh[so + 8] = bh1;
    *(half8*)&Bl[so] = bl0; *(half8*)&Bl[so + 8] = bl1;
    __syncthreads();

    half8 fah[4], fal[4], fbh[4], fbl[4];
#pragma unroll
    for (int i = 0; i < 4; ++i) {
      const int ao = (wm + i * 16 + i16) * RS + quad * 8;
      const int bo = (wn + i * 16 + i16) * RS + quad * 8;
      fah[i] = *(const half8*)&Ah[ao];
      fal[i] = *(const half8*)&Al[ao];
      fbh[i] = *(const half8*)&Bh[bo];
      fbl[i] = *(const half8*)&Bl[bo];
    }
#pragma unroll
    for (int im = 0; im < 4; ++im)
#pragma unroll
      for (int in = 0; in < 4; ++in) {
        acc1[im][in] = __builtin_amdgcn_mfma_f32_16x16x32_f16(
            fah[im], fbh[in], acc1[im][in], 0, 0, 0);
        acc2[im][in] = __builtin_amdgcn_mfma_f32_16x16x32_f16(
            fah[im], fbl[in], acc2[im][in], 0, 0, 0);
        acc2[im][in] = __builtin_amdgcn_mfma_f32_16x16x32_f16(
            fal[im], fbh[in], acc2[im][in], 0, 0, 0);
      }
  }

#pragma unroll
  for (int in = 0; in < 4; ++in) {
    const int col = bn + wn + in * 16 + i16;
    const float bv = bias[col];
#pragma unroll
    for (int im = 0; im < 4; ++im) {
#pragma unroll
      for (int reg = 0; reg < 4; ++reg) {
        const int row = bm + wm + im * 16 + quad * 4 + reg;
        float v = acc1[im][in][reg] + acc2[im][in][reg] * INV2048 + bv;
        v = v > 0.f ? v : 0.f;
        f16 hv = (f16)v;
        f16 lv = (f16)((v - (float)hv) * 2048.0f);
        H1[(size_t)row * N + col] = pack_hl(hv, lv);
      }
    }
  }
}

// ---------------------------------------------------------------- GEMM 2 (fallback)
__global__ __launch_bounds__(256, 2) void gemm2_fb_kernel(
    const unsigned* __restrict__ A, const float* __restrict__ B,
    const float* __restrict__ bias, const float* __restrict__ w3,
    float* __restrict__ ylogit, int M, int N, int K)
{
  __shared__ f16 Ah[BM * RS], Al[BM * RS], Bh[BN * RS], Bl[BN * RS];

  const int bn = blockIdx.x * BN;
  const int bm = blockIdx.y * BM;
  const int t = threadIdx.x;
  const int r = t >> 1;
  const int h = t & 1;

  const int lane = t & 63;
  const int wv = t >> 6;
  const int wm = (wv >> 1) * 64;
  const int wn = (wv & 1) * 64;
  const int i16 = lane & 15;
  const int quad = lane >> 4;

  f32x4 acc1[4][4] = {};
  f32x4 acc2[4][4] = {};

  const unsigned* Ag = A + (size_t)(bm + r) * K + h * 16;
  const float* Bg = B + (size_t)(bn + r) * K + h * 16;

  for (int k0 = 0; k0 < K; k0 += BK) {
    unsigned ua[16];
    float xb[16];
    *(uint4*)&ua[0]  = *(const uint4*)(Ag + k0);
    *(uint4*)&ua[4]  = *(const uint4*)(Ag + k0 + 4);
    *(uint4*)&ua[8]  = *(const uint4*)(Ag + k0 + 8);
    *(uint4*)&ua[12] = *(const uint4*)(Ag + k0 + 12);
    *(float4*)&xb[0]  = *(const float4*)(Bg + k0);
    *(float4*)&xb[4]  = *(const float4*)(Bg + k0 + 4);
    *(float4*)&xb[8]  = *(const float4*)(Bg + k0 + 8);
    *(float4*)&xb[12] = *(const float4*)(Bg + k0 + 12);

    half8 ah0, ah1, al0, al1, bh0, bh1, bl0, bl1;
#pragma unroll
    for (int e = 0; e < 8; ++e) {
      ah0[e] = u2h((unsigned short)(ua[e] & 0xffffu));
      al0[e] = u2h((unsigned short)(ua[e] >> 16));
      ah1[e] = u2h((unsigned short)(ua[8 + e] & 0xffffu));
      al1[e] = u2h((unsigned short)(ua[8 + e] >> 16));
    }
    SPLIT16(xb, bh0, bh1, bl0, bl1);

    __syncthreads();
    const int so = r * RS + h * 16;
    *(half8*)&Ah[so] = ah0; *(half8*)&Ah[so + 8] = ah1;
    *(half8*)&Al[so] = al0; *(half8*)&Al[so + 8] = al1;
    *(half8*)&Bh[so] = bh0; *(half8*)&Bh[so + 8] = bh1;
    *(half8*)&Bl[so] = bl0; *(half8*)&Bl[so + 8] = bl1;
    __syncthreads();

    half8 fah[4], fal[4], fbh[4], fbl[4];
#pragma unroll
    for (int i = 0; i < 4; ++i) {
      const int ao = (wm + i * 16 + i16) * RS + quad * 8;
      const int bo = (wn + i * 16 + i16) * RS + quad * 8;
      fah[i] = *(const half8*)&Ah[ao];
      fal[i] = *(const half8*)&Al[ao];
      fbh[i] = *(const half8*)&Bh[bo];
      fbl[i] = *(const half8*)&Bl[bo];
    }
#pragma unroll
    for (int im = 0; im < 4; ++im)
#pragma unroll
      for (int in = 0; in < 4; ++in) {
        acc1[im][in] = __builtin_amdgcn_mfma_f32_16x16x32_f16(
            fah[im], fbh[in], acc1[im][in], 0, 0, 0);
        acc2[im][in] = __builtin_amdgcn_mfma_f32_16x16x32_f16(
            fah[im], fbl[in], acc2[im][in], 0, 0, 0);
        acc2[im][in] = __builtin_amdgcn_mfma_f32_16x16x32_f16(
            fal[im], fbh[in], acc2[im][in], 0, 0, 0);
      }
  }

  float psum[4][4];
#pragma unroll
  for (int im = 0; im < 4; ++im)
#pragma unroll
    for (int reg = 0; reg < 4; ++reg) psum[im][reg] = 0.f;

#pragma unroll
  for (int in = 0; in < 4; ++in) {
    const int col = bn + wn + in * 16 + i16;
    const float bv = bias[col];
    const float wv3 = w3[col];
#pragma unroll
    for (int im = 0; im < 4; ++im)
#pragma unroll
      for (int reg = 0; reg < 4; ++reg) {
        float v = acc1[im][in][reg] + acc2[im][in][reg] * INV2048 + bv;
        v = v > 0.f ? v : 0.f;
        psum[im][reg] = fmaf(v, wv3, psum[im][reg]);
      }
  }
#pragma unroll
  for (int off = 1; off < 16; off <<= 1)
#pragma unroll
    for (int im = 0; im < 4; ++im)
#pragma unroll
      for (int reg = 0; reg < 4; ++reg)
        psum[im][reg] += __shfl_xor(psum[im][reg], off, 64);

  if (i16 == 0) {
#pragma unroll
    for (int im = 0; im < 4; ++im)
#pragma unroll
      for (int reg = 0; reg < 4; ++reg)
        atomicAdd(&ylogit[bm + wm + im * 16 + quad * 4 + reg], psum[im][reg]);
  }
}

// ---------------------------------------------------------------- sigmoid
__global__ void sigmoid_kernel(const float* __restrict__ logit,
                               const float* __restrict__ b3,
                               float* __restrict__ ysoft, int n)
{
  int i = blockIdx.x * blockDim.x + threadIdx.x;
  if (i < n) {
    float x = logit[i] + b3[0];
    ysoft[i] = 1.f / (1.f + expf(-x));
  }
}

// ------------------------------------------------------------------ rank
__global__ __launch_bounds__(256) void rank_kernel(
    const float* __restrict__ ysoft, float* __restrict__ yhard,
    const int* __restrict__ kptr, int S)
{
  __shared__ float row[2048];
  const int b = blockIdx.x;
  const int part = blockIdx.y;
  const float* y = ysoft + (size_t)b * S;
  float* out = yhard + (size_t)b * S;
  const int kk = *kptr;

  for (int i = threadIdx.x; i < S; i += 256) row[i] = y[i];
  __syncthreads();

  const int j = part * 256 + threadIdx.x;
  if (j >= S) return;
  if (j == 0) { out[0] = 1.0f; return; }
  const float v = row[j];
  int cnt = 1;  // token 0 always strictly smaller
  for (int i = 1; i < S; ++i) {
    float u = row[i];
    if (u < v || (u == v && i < j)) ++cnt;
  }
  out[j] = (cnt < kk) ? 1.0f : 0.0f;
}

// ------------------------------------------------------------------ launch
extern "C" void kernel_launch(void* const* d_in, const int* in_sizes, int n_in,
                              void* d_out, int out_size, void* d_ws, size_t ws_size,
                              hipStream_t stream)
{
  const float* X  = (const float*)d_in[0];
  const float* W1 = (const float*)d_in[1];
  const float* b1 = (const float*)d_in[2];
  const float* W2 = (const float*)d_in[3];
  const float* b2 = (const float*)d_in[4];
  const float* W3 = (const float*)d_in[5];
  const float* b3 = (const float*)d_in[6];
  const int*  kpt = (const int*)d_in[7];

  const int D = 768;
  const int M = in_sizes[0] / D;   // 131072
  const int S = 2048;
  const int Bb = M / S;            // 64

  float* ylogit = (float*)d_out;           // first M floats (scratch)
  float* yhard  = (float*)d_out;
  float* ysoft  = ((float*)d_out) + M;

  const size_t nX = (size_t)M * D;
  const size_t nW = (size_t)D * D;
  const size_t needA = (4 * nX + 4 * nW) * sizeof(f16);  // ~810 MB

  dim3 blk(256);

  if (ws_size >= needA) {
    f16* Xh  = (f16*)d_ws;
    f16* Xl  = Xh + nX;
    f16* W1h = Xl + nX;
    f16* W1l = W1h + nW;
    f16* W2h = W1l + nW;
    f16* W2l = W2h + nW;
    f16* H1h = W2l + nW;
    f16* H1l = H1h + nX;

    presplit_kernel<<<dim3(2048), blk, 0, stream>>>(X, Xh, Xl, (int)nX);
    presplit_kernel<<<dim3(288), blk, 0, stream>>>(W1, W1h, W1l, (int)nW);
    presplit_kernel<<<dim3(288), blk, 0, stream>>>(W2, W2h, W2l, (int)nW);
    hipMemsetAsync(ylogit, 0, (size_t)M * sizeof(float), stream);

    dim3 g((D / BN) * (M / BM));  // 6144, 1-D (decoded + XCD-remapped in-kernel)
    gemm_split_kernel<0><<<g, blk, 0, stream>>>(
        Xh, Xl, W1h, W1l, b1, nullptr, H1h, H1l, nullptr, M, D, D);
    gemm_split_kernel<1><<<g, blk, 0, stream>>>(
        H1h, H1l, W2h, W2l, b2, W3, nullptr, nullptr, ylogit, M, D, D);
  } else {
    // Fallback: v1 pipeline (packed {hi,lo} H1 in ws, in-kernel split).
    unsigned* H1 = (unsigned*)d_ws;
    hipMemsetAsync(ylogit, 0, (size_t)M * sizeof(float), stream);
    dim3 g(D / BN, M / BM);
    gemm1_fb_kernel<<<g, blk, 0, stream>>>(X, W1, b1, H1, M, D, D);
    gemm2_fb_kernel<<<g, blk, 0, stream>>>(H1, W2, b2, W3, ylogit, M, D, D);
  }

  sigmoid_kernel<<<dim3((M + 255) / 256), blk, 0, stream>>>(ylogit, b3, ysoft, M);
  rank_kernel<<<dim3(Bb, 8), blk, 0, stream>>>(ysoft, yhard, kpt, S);
}

// Round 3
// 1644.814 us; speedup vs baseline: 1.2663x; 1.0541x over previous
//
#include <hip/hip_runtime.h>
#include <math.h>

// BERTStudentPruner on MI355X — fp16x2 split-precision MFMA GEMMs, v4.
//
// v4 change (isolated): counted-vmcnt software pipeline (T4) replacing the
// __syncthreads()-drained double buffer. Per K-step:
//   ds_read frags(t) ; lgkmcnt(0) ; s_barrier ; STAGE(t+2)->buf[t&1] ;
//   MFMA x48 ; vmcnt(8) ; s_barrier
// The end-of-iter wait is vmcnt(8): tile t+1's loads must land, tile t+2's
// 8 newest stay IN FLIGHT across the barrier (never drain to 0 in the main
// loop; tail peels to vmcnt(0)). Stage(t+2) gets ~1.5 iterations of flight
// to cover ~900-cyc HBM latency. v3's __syncthreads forced vmcnt(0) every
// step -> pipeline depth <1 iter -> MfmaUtil stuck at 33%.
//
// Numerics bit-identical to v2/v3: a = a_hi + 2^-11*a_lo, 3 MFMAs/tile,
// lo*lo dropped. X,W1,W2 pre-split to f16 hi/lo planes; H1 as two planes;
// zero conversion VALU in the GEMM loops. LDS XOR swizzle (2-way, free)
// applied source-side for global_load_lds + read-side, as in v3.

typedef _Float16 f16;
typedef __attribute__((ext_vector_type(8))) _Float16 half8;
typedef __attribute__((ext_vector_type(4))) float f32x4;

#define BM 128
#define BN 128
#define BK 32
#define RS 40          // fallback-path LDS row stride (pad 32->40)
#define INV2048 (1.0f/2048.0f)
#define PLANE (BM * BK)          // 4096 f16 = 8192 B per plane
#define BUFH  (4 * PLANE)        // 4 planes per buffer (f16 elems)

typedef __attribute__((address_space(3))) unsigned lds_u32;
typedef __attribute__((address_space(1))) const unsigned gbl_u32;
#define GLOAD16(g, l) __builtin_amdgcn_global_load_lds((gbl_u32*)(g), (lds_u32*)(l), 16, 0, 0)

union HU { unsigned short u; f16 f; };
static __device__ inline unsigned pack_hl(f16 h, f16 l) {
  HU a, b; a.f = h; b.f = l;
  return (unsigned)a.u | ((unsigned)b.u << 16);
}
static __device__ inline f16 u2h(unsigned short u) { HU c; c.u = u; return c.f; }

// Split 16 fp32 (in x[16]) into hi/lo half8 pairs (fallback path).
#define SPLIT16(x, h0, h1, l0, l1)                                   \
  {                                                                  \
    _Pragma("unroll")                                                \
    for (int e = 0; e < 8; ++e) {                                    \
      f16 ha = (f16)x[e];      float fa = (float)ha;                 \
      f16 hb = (f16)x[8 + e];  float fb = (float)hb;                 \
      h0[e] = ha; l0[e] = (f16)((x[e] - fa) * 2048.0f);              \
      h1[e] = hb; l1[e] = (f16)((x[8 + e] - fb) * 2048.0f);          \
    }                                                                \
  }

// ------------------------------------------------------------- presplit
__global__ __launch_bounds__(256) void presplit_kernel(
    const float* __restrict__ src, f16* __restrict__ hi,
    f16* __restrict__ lo, int n)
{
  int i = (blockIdx.x * 256 + threadIdx.x) * 8;
  const int stride = gridDim.x * 256 * 8;
  for (; i + 7 < n; i += stride) {
    float4 x0 = *(const float4*)(src + i);
    float4 x1 = *(const float4*)(src + i + 4);
    float xs[8] = {x0.x, x0.y, x0.z, x0.w, x1.x, x1.y, x1.z, x1.w};
    half8 h, l;
#pragma unroll
    for (int e = 0; e < 8; ++e) {
      f16 hv = (f16)xs[e];
      h[e] = hv;
      l[e] = (f16)((xs[e] - (float)hv) * 2048.0f);
    }
    *(half8*)(hi + i) = h;
    *(half8*)(lo + i) = l;
  }
}

// -------------------------------------------------- split-plane GEMM
// A planes [M,K] f16 hi/lo, B planes [N,K] f16 hi/lo.
// FUSE=0: out = relu(A@B^T + bias) split to Oh/Ol planes  (gemm1)
// FUSE=1: ylogit += relu(A@B^T + bias) @ w3 (atomicAdd)   (gemm2)
template<int FUSE>
__global__ __launch_bounds__(256, 2) void gemm_split_kernel(
    const f16* __restrict__ Ahg, const f16* __restrict__ Alg,
    const f16* __restrict__ Bhg, const f16* __restrict__ Blg,
    const float* __restrict__ bias, const float* __restrict__ w3,
    f16* __restrict__ Oh, f16* __restrict__ Ol,
    float* __restrict__ ylogit, int M, int N, int K)
{
  // Double-buffered: 2 x {Ah,Al,Bh,Bl} planes, linear layout, 64 KB.
  __shared__ f16 L[2 * BUFH];

  // XCD-bijective remap (gridDim.x % 8 == 0).
  const int nwg = gridDim.x;
  const int cpx = nwg >> 3;
  const int n = ((int)blockIdx.x & 7) * cpx + ((int)blockIdx.x >> 3);
  const int nbn = N / BN;
  const int bn = (n % nbn) * BN;
  const int bm = (n / nbn) * BM;

  const int t = threadIdx.x;
  const int lane = t & 63;
  const int wv = t >> 6;
  const int wm = (wv >> 1) * 64;
  const int wn = (wv & 1) * 64;
  const int i16 = lane & 15;
  const int quad = lane >> 4;
  // Read-side XOR swizzle: k-chunk `quad` of row r lives in LDS slot
  // quad ^ ((r>>1)&3); slot8 = (i16&1)*4 + swq bijective over i16=0..7
  // -> 2-way bank aliasing (free). Verified: conflicts 3.8e7 -> 0.
  const int swq = quad ^ ((i16 >> 1) & 3);

  // Staging: wave wv stages plane wv; LDS dest LINEAR in lane order,
  // swizzle applied on the SOURCE chunk index (same involution).
  const int srow = lane >> 2;                      // row in 16-row group
  const int sch = (lane & 3) ^ ((srow >> 1) & 3);  // inverse-swizzled chunk
  const f16* sp;
  if (wv == 0)      sp = Ahg + (size_t)bm * K;
  else if (wv == 1) sp = Alg + (size_t)bm * K;
  else if (wv == 2) sp = Bhg + (size_t)bn * K;
  else              sp = Blg + (size_t)bn * K;
  const f16* sbase = sp + (size_t)srow * K + sch * 8;

#define STAGE(k0, buf)                                                \
  {                                                                   \
    char* lwb_ = (char*)L + (buf) * 32768 + wv * 8192;                \
    _Pragma("unroll")                                                 \
    for (int j = 0; j < 8; ++j)                                       \
      GLOAD16(sbase + (size_t)j * 16 * K + (k0), lwb_ + j * 1024);    \
  }

  f32x4 acc1[4][4] = {};
  f32x4 acc2[4][4] = {};

  // Prologue: tiles 0 and 1 in flight (16 outstanding); wait tile 0 only.
  STAGE(0, 0);
  STAGE(BK, 1);
  asm volatile("s_waitcnt vmcnt(8)" ::: "memory");
  __builtin_amdgcn_s_barrier();

  const int nt = K / BK;
  for (int tt = 0; tt < nt; ++tt) {
    __builtin_amdgcn_sched_barrier(0);
    const f16* Lb  = L + (tt & 1) * BUFH;
    const f16* LAh = Lb;
    const f16* LAl = Lb + PLANE;
    const f16* LBh = Lb + 2 * PLANE;
    const f16* LBl = Lb + 3 * PLANE;

    half8 fah[4], fal[4], fbh[4], fbl[4];
#pragma unroll
    for (int i = 0; i < 4; ++i) {
      const int ao = (wm + i * 16 + i16) * BK + swq * 8;
      const int bo = (wn + i * 16 + i16) * BK + swq * 8;
      fah[i] = *(const half8*)&LAh[ao];
      fal[i] = *(const half8*)&LAl[ao];
      fbh[i] = *(const half8*)&LBh[bo];
      fbl[i] = *(const half8*)&LBl[bo];
    }
    // All 16 ds_reads done -> safe for every wave to overwrite buf[tt&1].
    asm volatile("s_waitcnt lgkmcnt(0)" ::: "memory");
    __builtin_amdgcn_sched_barrier(0);
    __builtin_amdgcn_s_barrier();

    // Issue tile t+2 into the buffer we just finished reading; it flies
    // through MFMA(t) + all of iter t+1 (~1.5 iters) before being needed.
    if (tt + 2 < nt) STAGE((tt + 2) * BK, tt & 1);
    __builtin_amdgcn_sched_barrier(0);

#pragma unroll
    for (int im = 0; im < 4; ++im)
#pragma unroll
      for (int in = 0; in < 4; ++in) {
        acc1[im][in] = __builtin_amdgcn_mfma_f32_16x16x32_f16(
            fah[im], fbh[in], acc1[im][in], 0, 0, 0);
        acc2[im][in] = __builtin_amdgcn_mfma_f32_16x16x32_f16(
            fah[im], fbl[in], acc2[im][in], 0, 0, 0);
        acc2[im][in] = __builtin_amdgcn_mfma_f32_16x16x32_f16(
            fal[im], fbh[in], acc2[im][in], 0, 0, 0);
      }

    // End-of-iter: tile t+1 must have landed; tile t+2's 8 newest loads
    // stay in flight across the barrier (counted vmcnt — never 0 except
    // at the tail where no t+2 was issued).
    if (tt < nt - 1) {
      if (tt + 2 < nt) asm volatile("s_waitcnt vmcnt(8)" ::: "memory");
      else             asm volatile("s_waitcnt vmcnt(0)" ::: "memory");
      __builtin_amdgcn_s_barrier();
    }
  }
#undef STAGE

  if (FUSE == 0) {
    // relu(acc + bias), split to planes.
#pragma unroll
    for (int in = 0; in < 4; ++in) {
      const int col = bn + wn + in * 16 + i16;
      const float bv = bias[col];
#pragma unroll
      for (int im = 0; im < 4; ++im)
#pragma unroll
        for (int reg = 0; reg < 4; ++reg) {
          const int row = bm + wm + im * 16 + quad * 4 + reg;
          float v = acc1[im][in][reg] + acc2[im][in][reg] * INV2048 + bv;
          v = v > 0.f ? v : 0.f;
          f16 hv = (f16)v;
          Oh[(size_t)row * N + col] = hv;
          Ol[(size_t)row * N + col] = (f16)((v - (float)hv) * 2048.0f);
        }
    }
  } else {
    // relu(acc + bias) dot w3 over this tile's cols -> atomicAdd.
    float psum[4][4];
#pragma unroll
    for (int im = 0; im < 4; ++im)
#pragma unroll
      for (int reg = 0; reg < 4; ++reg) psum[im][reg] = 0.f;

#pragma unroll
    for (int in = 0; in < 4; ++in) {
      const int col = bn + wn + in * 16 + i16;
      const float bv = bias[col];
      const float wv3 = w3[col];
#pragma unroll
      for (int im = 0; im < 4; ++im)
#pragma unroll
        for (int reg = 0; reg < 4; ++reg) {
          float v = acc1[im][in][reg] + acc2[im][in][reg] * INV2048 + bv;
          v = v > 0.f ? v : 0.f;
          psum[im][reg] = fmaf(v, wv3, psum[im][reg]);
        }
    }
#pragma unroll
    for (int off = 1; off < 16; off <<= 1)
#pragma unroll
      for (int im = 0; im < 4; ++im)
#pragma unroll
        for (int reg = 0; reg < 4; ++reg)
          psum[im][reg] += __shfl_xor(psum[im][reg], off, 64);

    if (i16 == 0) {
#pragma unroll
      for (int im = 0; im < 4; ++im)
#pragma unroll
        for (int reg = 0; reg < 4; ++reg)
          atomicAdd(&ylogit[bm + wm + im * 16 + quad * 4 + reg], psum[im][reg]);
    }
  }
}

// ---------------------------------------------------------------- GEMM 1 (fallback)
__global__ __launch_bounds__(256, 2) void gemm1_fb_kernel(
    const float* __restrict__ A, const float* __restrict__ B,
    const float* __restrict__ bias, unsigned* __restrict__ H1,
    int M, int N, int K)
{
  __shared__ f16 Ah[BM * RS], Al[BM * RS], Bh[BN * RS], Bl[BN * RS];

  const int bn = blockIdx.x * BN;
  const int bm = blockIdx.y * BM;
  const int t = threadIdx.x;
  const int r = t >> 1;
  const int h = t & 1;

  const int lane = t & 63;
  const int wv = t >> 6;
  const int wm = (wv >> 1) * 64;
  const int wn = (wv & 1) * 64;
  const int i16 = lane & 15;
  const int quad = lane >> 4;

  f32x4 acc1[4][4] = {};
  f32x4 acc2[4][4] = {};

  const float* Ag = A + (size_t)(bm + r) * K + h * 16;
  const float* Bg = B + (size_t)(bn + r) * K + h * 16;

  for (int k0 = 0; k0 < K; k0 += BK) {
    float xa[16], xb[16];
    *(float4*)&xa[0]  = *(const float4*)(Ag + k0);
    *(float4*)&xa[4]  = *(const float4*)(Ag + k0 + 4);
    *(float4*)&xa[8]  = *(const float4*)(Ag + k0 + 8);
    *(float4*)&xa[12] = *(const float4*)(Ag + k0 + 12);
    *(float4*)&xb[0]  = *(const float4*)(Bg + k0);
    *(float4*)&xb[4]  = *(const float4*)(Bg + k0 + 4);
    *(float4*)&xb[8]  = *(const float4*)(Bg + k0 + 8);
    *(float4*)&xb[12] = *(const float4*)(Bg + k0 + 12);

    half8 ah0, ah1, al0, al1, bh0, bh1, bl0, bl1;
    SPLIT16(xa, ah0, ah1, al0, al1);
    SPLIT16(xb, bh0, bh1, bl0, bl1);

    __syncthreads();
    const int so = r * RS + h * 16;
    *(half8*)&Ah[so] = ah0; *(half8*)&Ah[so + 8] = ah1;
    *(half8*)&Al[so] = al0; *(half8*)&Al[so + 8] = al1;
    *(half8*)&Bh[so] = bh0; *(half8*)&Bh[so + 8] = bh1;
    *(half8*)&Bl[so] = bl0; *(half8*)&Bl[so + 8] = bl1;
    __syncthreads();

    half8 fah[4], fal[4], fbh[4], fbl[4];
#pragma unroll
    for (int i = 0; i < 4; ++i) {
      const int ao = (wm + i * 16 + i16) * RS + quad * 8;
      const int bo = (wn + i * 16 + i16) * RS + quad * 8;
      fah[i] = *(const half8*)&Ah[ao];
      fal[i] = *(const half8*)&Al[ao];
      fbh[i] = *(const half8*)&Bh[bo];
      fbl[i] = *(const half8*)&Bl[bo];
    }
#pragma unroll
    for (int im = 0; im < 4; ++im)
#pragma unroll
      for (int in = 0; in < 4; ++in) {
        acc1[im][in] = __builtin_amdgcn_mfma_f32_16x16x32_f16(
            fah[im], fbh[in], acc1[im][in], 0, 0, 0);
        acc2[im][in] = __builtin_amdgcn_mfma_f32_16x16x32_f16(
            fah[im], fbl[in], acc2[im][in], 0, 0, 0);
        acc2[im][in] = __builtin_amdgcn_mfma_f32_16x16x32_f16(
            fal[im], fbh[in], acc2[im][in], 0, 0, 0);
      }
  }

#pragma unroll
  for (int in = 0; in < 4; ++in) {
    const int col = bn + wn + in * 16 + i16;
    const float bv = bias[col];
#pragma unroll
    for (int im = 0; im < 4; ++im) {
#pragma unroll
      for (int reg = 0; reg < 4; ++reg) {
        const int row = bm + wm + im * 16 + quad * 4 + reg;
        float v = acc1[im][in][reg] + acc2[im][in][reg] * INV2048 + bv;
        v = v > 0.f ? v : 0.f;
        f16 hv = (f16)v;
        f16 lv = (f16)((v - (float)hv) * 2048.0f);
        H1[(size_t)row * N + col] = pack_hl(hv, lv);
      }
    }
  }
}

// ---------------------------------------------------------------- GEMM 2 (fallback)
__global__ __launch_bounds__(256, 2) void gemm2_fb_kernel(
    const unsigned* __restrict__ A, const float* __restrict__ B,
    const float* __restrict__ bias, const float* __restrict__ w3,
    float* __restrict__ ylogit, int M, int N, int K)
{
  __shared__ f16 Ah[BM * RS], Al[BM * RS], Bh[BN * RS], Bl[BN * RS];

  const int bn = blockIdx.x * BN;
  const int bm = blockIdx.y * BM;
  const int t = threadIdx.x;
  const int r = t >> 1;
  const int h = t & 1;

  const int lane = t & 63;
  const int wv = t >> 6;
  const int wm = (wv >> 1) * 64;
  const int wn = (wv & 1) * 64;
  const int i16 = lane & 15;
  const int quad = lane >> 4;

  f32x4 acc1[4][4] = {};
  f32x4 acc2[4][4] = {};

  const unsigned* Ag = A + (size_t)(bm + r) * K + h * 16;
  const float* Bg = B + (size_t)(bn + r) * K + h * 16;

  for (int k0 = 0; k0 < K; k0 += BK) {
    unsigned ua[16];
    float xb[16];
    *(uint4*)&ua[0]  = *(const uint4*)(Ag + k0);
    *(uint4*)&ua[4]  = *(const uint4*)(Ag + k0 + 4);
    *(uint4*)&ua[8]  = *(const uint4*)(Ag + k0 + 8);
    *(uint4*)&ua[12] = *(const uint4*)(Ag + k0 + 12);
    *(float4*)&xb[0]  = *(const float4*)(Bg + k0);
    *(float4*)&xb[4]  = *(const float4*)(Bg + k0 + 4);
    *(float4*)&xb[8]  = *(const float4*)(Bg + k0 + 8);
    *(float4*)&xb[12] = *(const float4*)(Bg + k0 + 12);

    half8 ah0, ah1, al0, al1, bh0, bh1, bl0, bl1;
#pragma unroll
    for (int e = 0; e < 8; ++e) {
      ah0[e] = u2h((unsigned short)(ua[e] & 0xffffu));
      al0[e] = u2h((unsigned short)(ua[e] >> 16));
      ah1[e] = u2h((unsigned short)(ua[8 + e] & 0xffffu));
      al1[e] = u2h((unsigned short)(ua[8 + e] >> 16));
    }
    SPLIT16(xb, bh0, bh1, bl0, bl1);

    __syncthreads();
    const int so = r * RS + h * 16;
    *(half8*)&Ah[so] = ah0; *(half8*)&Ah[so + 8] = ah1;
    *(half8*)&Al[so] = al0; *(half8*)&Al[so + 8] = al1;
    *(half8*)&Bh[so] = bh0; *(half8*)&Bh[so + 8] = bh1;
    *(half8*)&Bl[so] = bl0; *(half8*)&Bl[so + 8] = bl1;
    __syncthreads();

    half8 fah[4], fal[4], fbh[4], fbl[4];
#pragma unroll
    for (int i = 0; i < 4; ++i) {
      const int ao = (wm + i * 16 + i16) * RS + quad * 8;
      const int bo = (wn + i * 16 + i16) * RS + quad * 8;
      fah[i] = *(const half8*)&Ah[ao];
      fal[i] = *(const half8*)&Al[ao];
      fbh[i] = *(const half8*)&Bh[bo];
      fbl[i] = *(const half8*)&Bl[bo];
    }
#pragma unroll
    for (int im = 0; im < 4; ++im)
#pragma unroll
      for (int in = 0; in < 4; ++in) {
        acc1[im][in] = __builtin_amdgcn_mfma_f32_16x16x32_f16(
            fah[im], fbh[in], acc1[im][in], 0, 0, 0);
        acc2[im][in] = __builtin_amdgcn_mfma_f32_16x16x32_f16(
            fah[im], fbl[in], acc2[im][in], 0, 0, 0);
        acc2[im][in] = __builtin_amdgcn_mfma_f32_16x16x32_f16(
            fal[im], fbh[in], acc2[im][in], 0, 0, 0);
      }
  }

  float psum[4][4];
#pragma unroll
  for (int im = 0; im < 4; ++im)
#pragma unroll
    for (int reg = 0; reg < 4; ++reg) psum[im][reg] = 0.f;

#pragma unroll
  for (int in = 0; in < 4; ++in) {
    const int col = bn + wn + in * 16 + i16;
    const float bv = bias[col];
    const float wv3 = w3[col];
#pragma unroll
    for (int im = 0; im < 4; ++im)
#pragma unroll
      for (int reg = 0; reg < 4; ++reg) {
        float v = acc1[im][in][reg] + acc2[im][in][reg] * INV2048 + bv;
        v = v > 0.f ? v : 0.f;
        psum[im][reg] = fmaf(v, wv3, psum[im][reg]);
      }
  }
#pragma unroll
  for (int off = 1; off < 16; off <<= 1)
#pragma unroll
    for (int im = 0; im < 4; ++im)
#pragma unroll
      for (int reg = 0; reg < 4; ++reg)
        psum[im][reg] += __shfl_xor(psum[im][reg], off, 64);

  if (i16 == 0) {
#pragma unroll
    for (int im = 0; im < 4; ++im)
#pragma unroll
      for (int reg = 0; reg < 4; ++reg)
        atomicAdd(&ylogit[bm + wm + im * 16 + quad * 4 + reg], psum[im][reg]);
  }
}

// ---------------------------------------------------------------- sigmoid
__global__ void sigmoid_kernel(const float* __restrict__ logit,
                               const float* __restrict__ b3,
                               float* __restrict__ ysoft, int n)
{
  int i = blockIdx.x * blockDim.x + threadIdx.x;
  if (i < n) {
    float x = logit[i] + b3[0];
    ysoft[i] = 1.f / (1.f + expf(-x));
  }
}

// ------------------------------------------------------------------ rank
__global__ __launch_bounds__(256) void rank_kernel(
    const float* __restrict__ ysoft, float* __restrict__ yhard,
    const int* __restrict__ kptr, int S)
{
  __shared__ float row[2048];
  const int b = blockIdx.x;
  const int part = blockIdx.y;
  const float* y = ysoft + (size_t)b * S;
  float* out = yhard + (size_t)b * S;
  const int kk = *kptr;

  for (int i = threadIdx.x; i < S; i += 256) row[i] = y[i];
  __syncthreads();

  const int j = part * 256 + threadIdx.x;
  if (j >= S) return;
  if (j == 0) { out[0] = 1.0f; return; }
  const float v = row[j];
  int cnt = 1;  // token 0 always strictly smaller
  for (int i = 1; i < S; ++i) {
    float u = row[i];
    if (u < v || (u == v && i < j)) ++cnt;
  }
  out[j] = (cnt < kk) ? 1.0f : 0.0f;
}

// ------------------------------------------------------------------ launch
extern "C" void kernel_launch(void* const* d_in, const int* in_sizes, int n_in,
                              void* d_out, int out_size, void* d_ws, size_t ws_size,
                              hipStream_t stream)
{
  const float* X  = (const float*)d_in[0];
  const float* W1 = (const float*)d_in[1];
  const float* b1 = (const float*)d_in[2];
  const float* W2 = (const float*)d_in[3];
  const float* b2 = (const float*)d_in[4];
  const float* W3 = (const float*)d_in[5];
  const float* b3 = (const float*)d_in[6];
  const int*  kpt = (const int*)d_in[7];

  const int D = 768;
  const int M = in_sizes[0] / D;   // 131072
  const int S = 2048;
  const int Bb = M / S;            // 64

  float* ylogit = (float*)d_out;           // first M floats (scratch)
  float* yhard  = (float*)d_out;
  float* ysoft  = ((float*)d_out) + M;

  const size_t nX = (size_t)M * D;
  const size_t nW = (size_t)D * D;
  const size_t needA = (4 * nX + 4 * nW) * sizeof(f16);  // ~810 MB

  dim3 blk(256);

  if (ws_size >= needA) {
    f16* Xh  = (f16*)d_ws;
    f16* Xl  = Xh + nX;
    f16* W1h = Xl + nX;
    f16* W1l = W1h + nW;
    f16* W2h = W1l + nW;
    f16* W2l = W2h + nW;
    f16* H1h = W2l + nW;
    f16* H1l = H1h + nX;

    presplit_kernel<<<dim3(2048), blk, 0, stream>>>(X, Xh, Xl, (int)nX);
    presplit_kernel<<<dim3(288), blk, 0, stream>>>(W1, W1h, W1l, (int)nW);
    presplit_kernel<<<dim3(288), blk, 0, stream>>>(W2, W2h, W2l, (int)nW);
    hipMemsetAsync(ylogit, 0, (size_t)M * sizeof(float), stream);

    dim3 g((D / BN) * (M / BM));  // 6144, 1-D (decoded + XCD-remapped in-kernel)
    gemm_split_kernel<0><<<g, blk, 0, stream>>>(
        Xh, Xl, W1h, W1l, b1, nullptr, H1h, H1l, nullptr, M, D, D);
    gemm_split_kernel<1><<<g, blk, 0, stream>>>(
        H1h, H1l, W2h, W2l, b2, W3, nullptr, nullptr, ylogit, M, D, D);
  } else {
    // Fallback: v1 pipeline (packed {hi,lo} H1 in ws, in-kernel split).
    unsigned* H1 = (unsigned*)d_ws;
    hipMemsetAsync(ylogit, 0, (size_t)M * sizeof(float), stream);
    dim3 g(D / BN, M / BM);
    gemm1_fb_kernel<<<g, blk, 0, stream>>>(X, W1, b1, H1, M, D, D);
    gemm2_fb_kernel<<<g, blk, 0, stream>>>(H1, W2, b2, W3, ylogit, M, D, D);
  }

  sigmoid_kernel<<<dim3((M + 255) / 256), blk, 0, stream>>>(ylogit, b3, ysoft, M);
  rank_kernel<<<dim3(Bb, 8), blk, 0, stream>>>(ysoft, yhard, kpt, S);
}